// Round 1
// 532.630 us; speedup vs baseline: 1.0360x; 1.0360x over previous
//
#include <hip/hip_runtime.h>
#include <math.h>

#define LQ_ 5440
#define NB_ 8
#define NQ_ (NB_ * LQ_)   // 43520
#define D_  256
#define NH_ 8
#define HD_ 32

typedef __attribute__((ext_vector_type(8))) short short8;
typedef __attribute__((ext_vector_type(4))) float f32x4;

__device__ __forceinline__ ushort f2bf(float f) {
    union { float f; unsigned u; } v; v.f = f;
    unsigned u = v.u;
    unsigned r = (u + 0x7FFFu + ((u >> 16) & 1u)) >> 16;
    return (ushort)r;
}

// async global->LDS, 16 B per lane. LDS dest = wave-uniform base + lane*16.
__device__ __forceinline__ void gload_lds16(const void* g, void* l) {
    __builtin_amdgcn_global_load_lds(
        (const __attribute__((address_space(1))) void*)g,
        (__attribute__((address_space(3))) void*)l, 16, 0, 0);
}

// ---------------------------------------------------------------------------
// Input prep: s_bf = bf16(src), q_bf = bf16(src+pos). 4 elems/thread.
// ---------------------------------------------------------------------------
__global__ void make_bf_inputs(const float* __restrict__ src, const float* __restrict__ pos,
                               ushort* __restrict__ s_bf, ushort* __restrict__ q_bf) {
    const int i = blockIdx.x * blockDim.x + threadIdx.x;
    const float4 s = ((const float4*)src)[i];
    const float4 p = ((const float4*)pos)[i];
    ushort4 a, b;
    a.x = f2bf(s.x); a.y = f2bf(s.y); a.z = f2bf(s.z); a.w = f2bf(s.w);
    b.x = f2bf(s.x + p.x); b.y = f2bf(s.y + p.y); b.z = f2bf(s.z + p.z); b.w = f2bf(s.w + p.w);
    ((ushort4*)s_bf)[i] = a;
    ((ushort4*)q_bf)[i] = b;
}

// ---------------------------------------------------------------------------
// Weight transpose + bf16 cast: W [K,N] fp32 -> Wt [N,K] bf16.
// ---------------------------------------------------------------------------
__global__ void transpose_w(const float* __restrict__ W, ushort* __restrict__ Wt, int K, int N) {
    __shared__ float tile[32][33];
    const int bx = blockIdx.x;   // n tile
    const int by = blockIdx.y;   // k tile
    const int tx = threadIdx.x;  // 0..31
    const int ty = threadIdx.y;  // 0..7
    for (int i = ty; i < 32; i += 8)
        tile[i][tx] = W[(size_t)(by * 32 + i) * N + bx * 32 + tx];
    __syncthreads();
    for (int i = ty; i < 32; i += 8)
        Wt[(size_t)(bx * 32 + i) * K + by * 32 + tx] = f2bf(tile[tx][i]);
}

// ---------------------------------------------------------------------------
// MFMA GEMM: C[M,N] = A[M,K](bf16) @ Bt[N,K](bf16)^T + bias, opt ReLU.
// 128x128 tile, BK=64, 4 waves, 4x4 16x16x32 tiles/wave.
// m97 structure: global_load_lds width-16 staging into LINEAR LDS [128][64].
// grid = (N/BN, M/BM): N-tile is the fast axis so neighboring blocks share
// the A panel in L2.
// ---------------------------------------------------------------------------
#define BM 128
#define BN 128
#define BK 64

__global__ __launch_bounds__(256)
void mfma_gemm(const ushort* __restrict__ A, const ushort* __restrict__ Bt,
               const float* __restrict__ bias, float* __restrict__ Cf,
               ushort* __restrict__ Cb, int N, int K, int relu) {
    __shared__ ushort lA[BM * BK];   // 16 KiB, linear (required by global_load_lds)
    __shared__ ushort lB[BN * BK];
    const int t    = threadIdx.x;
    const int col0 = blockIdx.x * BN;
    const int row0 = blockIdx.y * BM;
    const int w    = t >> 6;
    const int lane = t & 63;
    const int lr   = lane & 15;
    const int quad = lane >> 4;
    const int wm   = (w >> 1) * 64;
    const int wn   = (w & 1) * 64;

    f32x4 acc[4][4];
    #pragma unroll
    for (int i = 0; i < 4; ++i)
        #pragma unroll
        for (int j = 0; j < 4; ++j)
            acc[i][j] = (f32x4){0.f, 0.f, 0.f, 0.f};

    // staging geometry: lane t covers row (t>>3)+32g, elems (t&7)*8..+7
    // -> LDS byte t*16 + g*4096 == wave base (w*1024 + g*4096) + lane*16.
    const int sr = t >> 3;
    const int sc = (t & 7) * 8;
    const size_t aoff = (size_t)(row0 + sr) * K + sc;
    const size_t boff = (size_t)(col0 + sr) * K + sc;
    char* lAw = (char*)lA + w * 1024;
    char* lBw = (char*)lB + w * 1024;

    for (int k0 = 0; k0 < K; k0 += BK) {
        __syncthreads();   // protect prev iter's reads; also drains vmcnt->LDS
        #pragma unroll
        for (int g = 0; g < 4; ++g) {
            gload_lds16(A  + aoff + k0 + (size_t)g * 32 * K, lAw + g * 4096);
            gload_lds16(Bt + boff + k0 + (size_t)g * 32 * K, lBw + g * 4096);
        }
        __syncthreads();   // compiler emits s_waitcnt vmcnt(0) before barrier
        #pragma unroll
        for (int kk = 0; kk < 2; ++kk) {
            short8 af[4], bfr[4];
            #pragma unroll
            for (int i = 0; i < 4; ++i)
                af[i] = *(const short8*)(lA + (wm + i * 16 + lr) * BK + kk * 32 + quad * 8);
            #pragma unroll
            for (int j = 0; j < 4; ++j)
                bfr[j] = *(const short8*)(lB + (wn + j * 16 + lr) * BK + kk * 32 + quad * 8);
            #pragma unroll
            for (int i = 0; i < 4; ++i)
                #pragma unroll
                for (int j = 0; j < 4; ++j)
                    acc[i][j] = __builtin_amdgcn_mfma_f32_16x16x32_bf16(af[i], bfr[j], acc[i][j], 0, 0, 0);
        }
    }

    #pragma unroll
    for (int j = 0; j < 4; ++j) {
        const int col = col0 + wn + j * 16 + lr;
        const float bb = bias ? bias[col] : 0.f;
        #pragma unroll
        for (int i = 0; i < 4; ++i) {
            const int rbase = row0 + wm + i * 16 + quad * 4;
            #pragma unroll
            for (int r = 0; r < 4; ++r) {
                float v = acc[i][j][r] + bb;
                if (relu) v = fmaxf(v, 0.f);
                if (Cf) Cf[(size_t)(rbase + r) * N + col] = v;
                else    Cb[(size_t)(rbase + r) * N + col] = f2bf(v);
            }
        }
    }
}

// ---------------------------------------------------------------------------
// Fused softmax + deformable bilinear sampling.
// Block = 256 threads, 2 queries/block.
// comb: per-query row of 384 fp32 = [offsets(256) | attn logits(128)],
// biases (b_off, b_attn) folded in here (GEMM ran bias-free).
// Phase 1: thread u=(h,p): softmax + 4 corner BYTE offsets + 4 folded wts.
// Phase 2: thread u=(h,d2): addresses are sgpr_base + u32 byte offset ->
//          saddr-form global_load_dword, 1 VALU of addressing per corner.
// ---------------------------------------------------------------------------
__global__ __launch_bounds__(256)
void msda_sample(const ushort* __restrict__ value, const float* __restrict__ comb,
                 const float* __restrict__ b_off, const float* __restrict__ b_attn,
                 const float* __restrict__ refp, ushort* __restrict__ out) {
    __shared__ int   s_addr[256][4];   // byte offsets into value
    __shared__ float s_w[256][4];

    const int t  = threadIdx.x;
    const int tq = t >> 7;          // 0..1
    const int u  = t & 127;
    const int nq = blockIdx.x * 2 + tq;
    const int n  = nq / LQ_;

    // ---------------- phase 1: (h,p) ----------------
    {
        const int h = u >> 4;
        const int p = u & 15;
        const int l = p >> 2;

        const int starts[4] = {0, 4096, 5120, 5376};
        const int Wl = 64 >> l;

        // softmax over 16 points (bias folded here; GEMM wrote raw q@W)
        float a = comb[(size_t)nq * 384 + 256 + u] + b_attn[u];
        float m = a;
        #pragma unroll
        for (int o = 8; o > 0; o >>= 1) m = fmaxf(m, __shfl_xor(m, o));
        float e = __expf(a - m);
        float s = e;
        #pragma unroll
        for (int o = 8; o > 0; o >>= 1) s += __shfl_xor(s, o);
        const float wgt = e / s;

        const float rx = refp[(size_t)nq * 8 + l * 2 + 0];
        const float ry = refp[(size_t)nq * 8 + l * 2 + 1];
        const float ox = comb[(size_t)nq * 384 + u * 2 + 0] + b_off[u * 2 + 0];
        const float oy = comb[(size_t)nq * 384 + u * 2 + 1] + b_off[u * 2 + 1];

        const float fw = (float)Wl;
        const float x  = (rx + ox / fw) * fw - 0.5f;
        const float y  = (ry + oy / fw) * fw - 0.5f;
        const float x0f = floorf(x), y0f = floorf(y);
        const int   x0 = (int)x0f, y0 = (int)y0f;
        const float wx1 = x - x0f, wy1 = y - y0f;
        const float wx0 = 1.f - wx1, wy0 = 1.f - wy1;

        const float xm0 = (x0 >= 0 && x0 < Wl) ? 1.f : 0.f;
        const float xm1 = (x0 + 1 >= 0 && x0 + 1 < Wl) ? 1.f : 0.f;
        const float ym0 = (y0 >= 0 && y0 < Wl) ? 1.f : 0.f;
        const float ym1 = (y0 + 1 >= 0 && y0 + 1 < Wl) ? 1.f : 0.f;

        const int x0c = min(max(x0, 0), Wl - 1);
        const int x1c = min(max(x0 + 1, 0), Wl - 1);
        const int y0c = min(max(y0, 0), Wl - 1);
        const int y1c = min(max(y0 + 1, 0), Wl - 1);

        // BYTE offsets: value row = 256 bf16 = 512 B; head offset = h*32*2 = h*64 B
        const int base = (n * LQ_ + starts[l]) * 512 + h * 64;
        s_addr[t][0] = base + (y0c * Wl + x0c) * 512;
        s_addr[t][1] = base + (y0c * Wl + x1c) * 512;
        s_addr[t][2] = base + (y1c * Wl + x0c) * 512;
        s_addr[t][3] = base + (y1c * Wl + x1c) * 512;
        s_w[t][0] = wgt * wy0 * wx0 * ym0 * xm0;
        s_w[t][1] = wgt * wy0 * wx1 * ym0 * xm1;
        s_w[t][2] = wgt * wy1 * wx0 * ym1 * xm0;
        s_w[t][3] = wgt * wy1 * wx1 * ym1 * xm1;
    }
    __syncthreads();

    // ---------------- phase 2: (h,d2) ----------------
    {
        const int h   = u >> 4;
        const int d2  = u & 15;                  // uint index: elems 2*d2, 2*d2+1
        const int sb  = tq * 128 + h * 16;
        const uint dby = (uint)(d2 * 4);         // byte offset of this uint in row
        const char* vbase = (const char*)value;

        float acc0 = 0.f, acc1 = 0.f;
        #pragma unroll 8
        for (int p = 0; p < 16; ++p) {
            const int*   ap = s_addr[sb + p];
            const float* wp = s_w[sb + p];
            #pragma unroll
            for (int c = 0; c < 4; ++c) {
                const uint v = *(const uint*)(vbase + ((uint)ap[c] + dby));
                const float w = wp[c];
                union { uint u; float f; } lo, hi;
                lo.u = v << 16;            // bf16 lane 0 -> f32
                hi.u = v & 0xffff0000u;    // bf16 lane 1 -> f32
                acc0 = fmaf(lo.f, w, acc0);
                acc1 = fmaf(hi.f, w, acc1);
            }
        }
        const uint packed = (uint)f2bf(acc0) | ((uint)f2bf(acc1) << 16);
        ((uint*)out)[(size_t)nq * 128 + u] = packed;
    }
}

// ---------------------------------------------------------------------------
// x = LayerNorm(a + b); writes fp32 x and optionally bf16 x.
// ---------------------------------------------------------------------------
__global__ void add_ln(const float* __restrict__ a, const float* __restrict__ b,
                       const float* __restrict__ g, const float* __restrict__ be,
                       float* __restrict__ xf, ushort* __restrict__ xb) {
    const int row = blockIdx.x;
    const int t   = threadIdx.x;
    const size_t idx = (size_t)row * 256 + t;
    const float x = a[idx] + b[idx];

    __shared__ float sm[4];
    float v = x;
    #pragma unroll
    for (int o = 32; o > 0; o >>= 1) v += __shfl_down(v, o);
    if ((t & 63) == 0) sm[t >> 6] = v;
    __syncthreads();
    const float mu = (sm[0] + sm[1] + sm[2] + sm[3]) * (1.f / 256.f);
    __syncthreads();

    const float dx = x - mu;
    v = dx * dx;
    #pragma unroll
    for (int o = 32; o > 0; o >>= 1) v += __shfl_down(v, o);
    if ((t & 63) == 0) sm[t >> 6] = v;
    __syncthreads();
    const float var = (sm[0] + sm[1] + sm[2] + sm[3]) * (1.f / 256.f);

    const float y = dx * rsqrtf(var + 1e-5f) * g[t] + be[t];
    xf[idx] = y;
    if (xb) xb[idx] = f2bf(y);
}

// ---------------------------------------------------------------------------
extern "C" void kernel_launch(void* const* d_in, const int* in_sizes, int n_in,
                              void* d_out, int out_size, void* d_ws, size_t ws_size,
                              hipStream_t stream) {
    const float* src     = (const float*)d_in[0];
    const float* pos     = (const float*)d_in[1];
    const float* refp    = (const float*)d_in[2];
    const float* W_value = (const float*)d_in[4];
    const float* b_value = (const float*)d_in[5];
    const float* W_off   = (const float*)d_in[6];
    const float* b_off   = (const float*)d_in[7];
    const float* W_attn  = (const float*)d_in[8];
    const float* b_attn  = (const float*)d_in[9];
    const float* W_out   = (const float*)d_in[10];
    const float* b_out   = (const float*)d_in[11];
    const float* ln1g    = (const float*)d_in[12];
    const float* ln1b    = (const float*)d_in[13];
    const float* W1      = (const float*)d_in[14];
    const float* b1      = (const float*)d_in[15];
    const float* W2      = (const float*)d_in[16];
    const float* b2      = (const float*)d_in[17];
    const float* ln2g    = (const float*)d_in[18];
    const float* ln2b    = (const float*)d_in[19];
    float* out = (float*)d_out;
    char*  ws  = (char*)d_ws;

    // ---- workspace layout (byte offsets) ----
    const size_t SZ_BF = (size_t)NQ_ * 256 * 2;   // 22,282,240
    const size_t SZ_F  = (size_t)NQ_ * 256 * 4;   // 44,564,480
    ushort* s_bf    = (ushort*)(ws);                            // [0, 22.28M)
    ushort* q_bf    = (ushort*)(ws + SZ_BF);                    // [22.28M, 44.56M)
    ushort* val_bf  = (ushort*)(ws + 2 * SZ_BF);                // [44.56M, 66.85M)
    float*  comb    = (float*) (ws + 3 * SZ_BF);                // [66.85M, 133.69M)  NQ x 384 fp32
    ushort* samp_bf = (ushort*)(ws + 4 * SZ_BF + SZ_F);         // [133.69M, 155.98M)
    ushort* h_bf    = (ushort*)(ws);                            // overlays [0, 89.13M) — s/q/val/comb-head dead
    ushort* x_bf    = (ushort*)(ws + 3 * SZ_BF + SZ_F);         // overlays comb tail (dead after sampling)
    char*   wbase   = ws + 5 * SZ_BF + SZ_F;                    // 155.98M
    ushort* Wv_t    = (ushort*)(wbase);
    ushort* Woff_t  = (ushort*)(wbase + 131072);   // contiguous with Wattn_t -> one [384][256] Bt
    ushort* Wattn_t = (ushort*)(wbase + 262144);
    ushort* Wout_t  = (ushort*)(wbase + 327680);
    ushort* W1_t    = (ushort*)(wbase + 458752);
    ushort* W2_t    = (ushort*)(wbase + 983040);
    char*   fbase   = wbase + 1507328;
    float*  src2    = (float*)(fbase);                          // also ffn2
    float*  xf      = (float*)(fbase + SZ_F);

    // 0. bf16 inputs
    make_bf_inputs<<<dim3((NQ_ * 256 / 4) / 256), 256, 0, stream>>>(src, pos, s_bf, q_bf);
    // 0b. weight transposes (fp32 [K,N] -> bf16 [N,K])
    transpose_w<<<dim3(8, 8),  dim3(32, 8), 0, stream>>>(W_value, Wv_t,   256, 256);
    transpose_w<<<dim3(8, 8),  dim3(32, 8), 0, stream>>>(W_off,   Woff_t, 256, 256);
    transpose_w<<<dim3(4, 8),  dim3(32, 8), 0, stream>>>(W_attn,  Wattn_t,256, 128);
    transpose_w<<<dim3(8, 8),  dim3(32, 8), 0, stream>>>(W_out,   Wout_t, 256, 256);
    transpose_w<<<dim3(32, 8), dim3(32, 8), 0, stream>>>(W1,      W1_t,   256, 1024);
    transpose_w<<<dim3(8, 32), dim3(32, 8), 0, stream>>>(W2,      W2_t,   1024, 256);

    const int MT = NQ_ / BM;  // 340

    // 1. value = src @ Wv + bv  (bf16 out)
    mfma_gemm<<<dim3(2, MT), 256, 0, stream>>>(s_bf, Wv_t, b_value, nullptr, val_bf, 256, 256, 0);
    // 2. comb = q @ [Woff|Wattn]  (fp32, N=384, biases folded into msda_sample)
    mfma_gemm<<<dim3(3, MT), 256, 0, stream>>>(q_bf, Woff_t, nullptr, comb, nullptr, 384, 256, 0);
    // 3+4. fused softmax + sampling -> bf16
    msda_sample<<<dim3(NQ_ / 2), 256, 0, stream>>>(val_bf, comb, b_off, b_attn, refp, samp_bf);
    // 5. src2 = sampled @ Wout + bout (fp32)
    mfma_gemm<<<dim3(2, MT), 256, 0, stream>>>(samp_bf, Wout_t, b_out, src2, nullptr, 256, 256, 0);
    // 6. x = LN(src + src2) -> fp32 + bf16
    add_ln<<<dim3(NQ_), 256, 0, stream>>>(src, src2, ln1g, ln1b, xf, x_bf);
    // 7. h = relu(x @ W1 + b1) -> bf16
    mfma_gemm<<<dim3(8, MT), 256, 0, stream>>>(x_bf, W1_t, b1, nullptr, h_bf, 1024, 256, 1);
    // 8. ffn2 = h @ W2 + b2 -> fp32 (overlays src2)
    mfma_gemm<<<dim3(2, MT), 256, 0, stream>>>(h_bf, W2_t, b2, src2, nullptr, 256, 1024, 0);
    // 9. out = LN(x + ffn2)
    add_ln<<<dim3(NQ_), 256, 0, stream>>>(xf, src2, ln2g, ln2b, out, nullptr);
}